// Round 15
// baseline (824.910 us; speedup 1.0000x reference)
//
#include <hip/hip_runtime.h>
#include <hip/hip_bf16.h>
#include <math.h>

#define TSEQ 2048
#define DIN  32
#define HID  20
#define G4   80
#define TILE 16
#define NT   (TSEQ / TILE)
#define HSTR 68                 // padded hist row stride (floats), 16B-aligned rows
#define L2E  1.44269504088896340736f

typedef float v2f __attribute__((ext_vector_type(2)));
typedef unsigned int uint2v __attribute__((ext_vector_type(2)));
typedef _Float16 h2v __attribute__((ext_vector_type(2)));

#if __has_builtin(__builtin_amdgcn_exp2f)
#define EXP2(x) __builtin_amdgcn_exp2f(x)
#else
#define EXP2(x) __expf((x) * 0.69314718055994531f)
#endif

#if __has_builtin(__builtin_amdgcn_fdot2) && \
    (__has_builtin(__builtin_amdgcn_mov_dpp) || __has_builtin(__builtin_amdgcn_update_dpp)) && \
    __has_builtin(__builtin_amdgcn_perm)
#define USE_FDOT2 1
#else
#define USE_FDOT2 0
#endif

__device__ __forceinline__ float rl(float v, int l) {
    return __int_as_float(__builtin_amdgcn_readlane(__float_as_int(v), l));
}

__device__ __forceinline__ float sig2(float xs) {   // 1/(1+2^-xs), xs pre-scaled by log2e
    return __builtin_amdgcn_rcpf(1.0f + EXP2(-xs));
}

// cross-half (lane ^ 32) exchange via the gfx950 BUILTIN (hazard-safe; the
// inline-asm form caused the non-deterministic R3/R5/R6/R9 failures — R10
// confirmed the builtin fix). Order-agnostic: r.x + r.y - v = opposite half.
__device__ __forceinline__ float xhalf(float v) {
#if __has_builtin(__builtin_amdgcn_permlane32_swap)
    uint2v r = __builtin_amdgcn_permlane32_swap(__float_as_uint(v),
                                                __float_as_uint(v),
                                                false, false);
    return (__uint_as_float(r.x) + __uint_as_float(r.y)) - v;
#else
    return __shfl_xor(v, 32);
#endif
}

__device__ __forceinline__ float samp(const float* mu, const float* rho,
                                      const float* eps, int i) {
    return mu[i] + log1pf(__expf(rho[i])) * eps[i];
}

// quad_perm [1,1,3,3]: even lanes receive their odd neighbor's value (VALU DPP)
__device__ __forceinline__ int dpp_odd_to_even(int v) {
#if __has_builtin(__builtin_amdgcn_mov_dpp)
    return __builtin_amdgcn_mov_dpp(v, 0xF5, 0xf, 0xf, false);
#else
    return __builtin_amdgcn_update_dpp(0, v, 0xF5, 0xf, 0xf, false);
#endif
}

// ======================== 2 sequences per block ========================
// Consumer chain is dependency-latency-bound (~490 cy/step, R10-R14);
// interleave two independent sequences in the consumer wave so seq B's
// instructions issue inside seq A's stalls. Weights shared; xgr/state
// duplicated. Producer wave produces both sequences' xg tiles + flushes.
__global__ __launch_bounds__(128, 1) void blstm_pair(
    const float* __restrict__ x,
    const float* __restrict__ wih_mu, const float* __restrict__ wih_rho, const float* __restrict__ wih_eps,
    const float* __restrict__ whh_mu, const float* __restrict__ whh_rho, const float* __restrict__ whh_eps,
    const float* __restrict__ bmu,    const float* __restrict__ brho,    const float* __restrict__ beps,
    const float* __restrict__ wlin,   const float* __restrict__ blin,
    float* __restrict__ out, int B)
{
    __shared__ __align__(16) float lds_xg[2][2][TILE * G4];  // [seq][buf]
    __shared__ __align__(16) float lds_x[2][TILE * DIN];     // [seq] staging
    __shared__ __align__(16) float hist[2][64 * HSTR];       // [seq] h ring

    const int tid  = threadIdx.x;
    const int lane = tid & 63;
    const int bA   = blockIdx.x * 2;
    const int bB   = (bA + 1 < B) ? (bA + 1) : bA;   // odd B: benign duplicate
    const float* xrowA = x + (size_t)bA * TSEQ * DIN;
    const float* xrowB = x + (size_t)bB * TSEQ * DIN;
    float* outA = out + (size_t)bA * TSEQ;
    float* outB = out + (size_t)bB * TSEQ;

    if (tid < 64) {
        // ======================= CONSUMER (both recurrences) =======================
        const int p  = lane >> 5;                  // 0: (i,f) cols; 1: (g,o) cols
        const int k  = lane & 31;
        const int ke = (k < HID) ? k : (HID - 1);  // junk lanes mirror unit 19
        const int g1 = p * 40 + ke;                // i_k or g_k
        const int g2 = g1 + HID;                   // f_k or o_k
        const float sc1 = (p ? 2.0f : 1.0f) * L2E;
        const float sc2 = L2E;
        // act1 constants with 2*L2E folded into the HIGH-lane tanh output:
        //   low:  act1 = sig(i);  high: act1 = 2*L2E*tanh(g)
        const float aAct2 = p ? (4.0f * L2E) : 1.0f;
        const float cAct2 = p ? (-2.0f * L2E) : 0.0f;

#if USE_FDOT2
        // f16 j-pair weights (shared by both sequences), scales folded
        h2v w1h[HID / 2], w2h[HID / 2];
#pragma unroll
        for (int m = 0; m < HID / 2; ++m) {
            const int je = 2 * m, jo = 2 * m + 1;
            w1h[m] = (h2v){ (_Float16)(samp(whh_mu, whh_rho, whh_eps, je * G4 + g1) * sc1),
                            (_Float16)(samp(whh_mu, whh_rho, whh_eps, jo * G4 + g1) * sc1) };
            w2h[m] = (h2v){ (_Float16)(samp(whh_mu, whh_rho, whh_eps, je * G4 + g2) * sc2),
                            (_Float16)(samp(whh_mu, whh_rho, whh_eps, jo * G4 + g2) * sc2) };
        }
#else
        v2f w12e[HID / 2], w12o[HID / 2];
#pragma unroll
        for (int jj = 0; jj < HID / 2; ++jj) {
            const int je = 2 * jj, jo = 2 * jj + 1;
            w12e[jj] = (v2f){ samp(whh_mu, whh_rho, whh_eps, je * G4 + g1) * sc1,
                              samp(whh_mu, whh_rho, whh_eps, je * G4 + g2) * sc2 };
            w12o[jj] = (v2f){ samp(whh_mu, whh_rho, whh_eps, jo * G4 + g1) * sc1,
                              samp(whh_mu, whh_rho, whh_eps, jo * G4 + g2) * sc2 };
        }
#endif
        const int coff = p * 40 + ke * 2;

        float hA = 0.0f, cA = 0.0f, hB = 0.0f, cB = 0.0f;
        for (int kt = 0; kt < NT; ++kt) {
            __syncthreads();                       // tiles kt ready (both seqs)
            const float* xgpA = lds_xg[0][kt & 1];
            const float* xgpB = lds_xg[1][kt & 1];
            v2f xgrA[TILE], xgrB[TILE];
#pragma unroll
            for (int r = 0; r < TILE; ++r) {
                xgrA[r] = *(const v2f*)&xgpA[r * G4 + coff];
                xgrB[r] = *(const v2f*)&xgpB[r * G4 + coff];
            }

#pragma unroll
            for (int ti = 0; ti < TILE; ++ti) {
                const int t = kt * TILE + ti;
                float d1A, d2A, d1B, d2B;
#if USE_FDOT2
                // pack h -> f16 pairs on even lanes (both seqs, interleaved)
                const _Float16 hfA = (_Float16)hA;
                const _Float16 hfB = (_Float16)hB;
                const unsigned cvA = (unsigned)__builtin_bit_cast(unsigned short, hfA);
                const unsigned cvB = (unsigned)__builtin_bit_cast(unsigned short, hfB);
                const int      shA = dpp_odd_to_even((int)cvA);
                const int      shB = dpp_odd_to_even((int)cvB);
                const unsigned pkA = __builtin_amdgcn_perm((unsigned)shA, cvA, 0x05040100u);
                const unsigned pkB = __builtin_amdgcn_perm((unsigned)shB, cvB, 0x05040100u);

                int hpA[HID / 2], hpB[HID / 2];
#pragma unroll
                for (int m = 0; m < HID / 2; ++m) {
                    hpA[m] = __builtin_amdgcn_readlane((int)pkA, 2 * m);
                    hpB[m] = __builtin_amdgcn_readlane((int)pkB, 2 * m);
                }

                float d1aA = xgrA[ti].x, d2aA = xgrA[ti].y;
                float d1aB = xgrB[ti].x, d2aB = xgrB[ti].y;
                float d1bA = 0.0f, d2bA = 0.0f, d1bB = 0.0f, d2bB = 0.0f;
#pragma unroll
                for (int m = 0; m < 5; ++m) {
                    const h2v hvA = __builtin_bit_cast(h2v, hpA[m]);
                    const h2v hvB = __builtin_bit_cast(h2v, hpB[m]);
                    d1aA = __builtin_amdgcn_fdot2(hvA, w1h[m], d1aA, false);
                    d1aB = __builtin_amdgcn_fdot2(hvB, w1h[m], d1aB, false);
                    d2aA = __builtin_amdgcn_fdot2(hvA, w2h[m], d2aA, false);
                    d2aB = __builtin_amdgcn_fdot2(hvB, w2h[m], d2aB, false);
                }
#pragma unroll
                for (int m = 5; m < HID / 2; ++m) {
                    const h2v hvA = __builtin_bit_cast(h2v, hpA[m]);
                    const h2v hvB = __builtin_bit_cast(h2v, hpB[m]);
                    d1bA = __builtin_amdgcn_fdot2(hvA, w1h[m], d1bA, false);
                    d1bB = __builtin_amdgcn_fdot2(hvB, w1h[m], d1bB, false);
                    d2bA = __builtin_amdgcn_fdot2(hvA, w2h[m], d2bA, false);
                    d2bB = __builtin_amdgcn_fdot2(hvB, w2h[m], d2bB, false);
                }
                d1A = d1aA + d1bA;  d2A = d2aA + d2bA;
                d1B = d1aB + d1bB;  d2B = d2aB + d2bB;
#else
                float hjA[HID], hjB[HID];
#pragma unroll
                for (int j = 0; j < HID; ++j) {
                    hjA[j] = rl(hA, j);
                    hjB[j] = rl(hB, j);
                }
                v2f dA1 = xgrA[ti], dA2 = (v2f){0.0f, 0.0f};
                v2f dB1 = xgrB[ti], dB2 = (v2f){0.0f, 0.0f};
#pragma unroll
                for (int jj = 0; jj < HID / 2; ++jj) {
                    dA1 = __builtin_elementwise_fma((v2f){hjA[2*jj], hjA[2*jj]}, w12e[jj], dA1);
                    dB1 = __builtin_elementwise_fma((v2f){hjB[2*jj], hjB[2*jj]}, w12e[jj], dB1);
                    dA2 = __builtin_elementwise_fma((v2f){hjA[2*jj+1], hjA[2*jj+1]}, w12o[jj], dA2);
                    dB2 = __builtin_elementwise_fma((v2f){hjB[2*jj+1], hjB[2*jj+1]}, w12o[jj], dB2);
                }
                const v2f dSA = dA1 + dA2, dSB = dB1 + dB2;
                d1A = dSA.x; d2A = dSA.y; d1B = dSB.x; d2B = dSB.y;
#endif

                const float s1A   = sig2(d1A);
                const float s1B   = sig2(d1B);
                const float act1A = fmaf(s1A, aAct2, cAct2);
                const float act1B = fmaf(s1B, aAct2, cAct2);
                const float act2A = sig2(d2A);
                const float act2B = sig2(d2B);

                const float og1A = xhalf(act1A);
                const float og1B = xhalf(act1B);
                const float og2A = xhalf(act2A);
                const float og2B = xhalf(act2B);

                cA = fmaf(act2A, cA, act1A * og1A);
                cB = fmaf(act2B, cB, act1B * og1B);
                const float tcA = fmaf(2.0f, sig2(cA), -1.0f);
                const float tcB = fmaf(2.0f, sig2(cB), -1.0f);
                hA = og2A * tcA;
                hB = og2B * tcB;

                hist[0][(t & 63) * HSTR + lane] = hA;
                hist[1][(t & 63) * HSTR + lane] = hB;
            }
        }
        __syncthreads();                           // expose last tiles' hist
    } else {
        // ============ PRODUCER (both sequences' xg + output flush) ============
        const int cAc = lane;                      // columns 0..63
        const int cBc = 64 + (lane & 15);          // columns 64..79 ('o' tail)
        const float scA = ((cAc >= 40 && cAc < 60) ? 2.0f : 1.0f) * L2E;
        const float scB = L2E;

        float wA[DIN], wB[DIN];
#pragma unroll
        for (int d = 0; d < DIN; ++d) {
            wA[d] = samp(wih_mu, wih_rho, wih_eps, d * G4 + cAc) * scA;
            wB[d] = samp(wih_mu, wih_rho, wih_eps, d * G4 + cBc) * scB;
        }
        const float biasA = samp(bmu, brho, beps, cAc) * scA;
        const float biasB = samp(bmu, brho, beps, cBc) * scB;

        const int posA = ((cAc >= 40) ? 40 : 0) + (cAc % 20) * 2 + ((cAc / 20) & 1);
        const int posB = 40 + (cBc % 20) * 2 + 1;  // 'o' columns
        const int qs   = (lane >> 4) * 4;          // dotB step group

        float wl[HID];
#pragma unroll
        for (int j = 0; j < HID; ++j) wl[j] = wlin[j];
        const float bl = blin[0];

        // produce tile kt of sequence sq into lds_xg[sq][kt&1] (R7-proven body)
        auto produce = [&](int sq, int kt) {
            const float* xu = (sq ? xrowB : xrowA) + kt * TILE * DIN;
            float* xgb = lds_xg[sq][kt & 1];
            float* lx  = lds_x[sq];
            {
                const float4* src = (const float4*)xu;
                float4 v0 = src[lane * 2 + 0];
                float4 v1 = src[lane * 2 + 1];
                ((float4*)lx)[lane * 2 + 0] = v0;
                ((float4*)lx)[lane * 2 + 1] = v1;
            }
#pragma unroll
            for (int s = 0; s < TILE; ++s) {
                float a0 = 0.0f, a1 = 0.0f;
#pragma unroll
                for (int d = 0; d < 16; ++d) {
                    a0 = fmaf(xu[s * DIN + d],      wA[d],      a0);
                    a1 = fmaf(xu[s * DIN + d + 16], wA[d + 16], a1);
                }
                xgb[s * G4 + posA] = biasA + a0 + a1;
            }
#pragma unroll
            for (int jj = 0; jj < 4; ++jj) {
                const int s = qs + jj;
                const float4* xr = (const float4*)&lx[s * DIN];
                float a0 = 0.0f, a1 = 0.0f;
#pragma unroll
                for (int q = 0; q < 4; ++q) {
                    const float4 u0 = xr[q], u1 = xr[q + 4];
                    a0 = fmaf(u0.x, wB[q * 4 + 0],      a0);
                    a0 = fmaf(u0.y, wB[q * 4 + 1],      a0);
                    a0 = fmaf(u0.z, wB[q * 4 + 2],      a0);
                    a0 = fmaf(u0.w, wB[q * 4 + 3],      a0);
                    a1 = fmaf(u1.x, wB[16 + q * 4 + 0], a1);
                    a1 = fmaf(u1.y, wB[16 + q * 4 + 1], a1);
                    a1 = fmaf(u1.z, wB[16 + q * 4 + 2], a1);
                    a1 = fmaf(u1.w, wB[16 + q * 4 + 3], a1);
                }
                xgb[s * G4 + posB] = biasB + a0 + a1;
            }
        };

        auto flush = [&](int sq, int ft) {
            if (lane < TILE) {
                const int t = ft * TILE + lane;
                const float4* hr = (const float4*)&hist[sq][(t & 63) * HSTR];
                const float4 r0 = hr[0], r1 = hr[1], r2 = hr[2], r3 = hr[3], r4 = hr[4];
                float acc = bl;
                acc = fmaf(r0.x, wl[0],  acc); acc = fmaf(r0.y, wl[1],  acc);
                acc = fmaf(r0.z, wl[2],  acc); acc = fmaf(r0.w, wl[3],  acc);
                acc = fmaf(r1.x, wl[4],  acc); acc = fmaf(r1.y, wl[5],  acc);
                acc = fmaf(r1.z, wl[6],  acc); acc = fmaf(r1.w, wl[7],  acc);
                acc = fmaf(r2.x, wl[8],  acc); acc = fmaf(r2.y, wl[9],  acc);
                acc = fmaf(r2.z, wl[10], acc); acc = fmaf(r2.w, wl[11], acc);
                acc = fmaf(r3.x, wl[12], acc); acc = fmaf(r3.y, wl[13], acc);
                acc = fmaf(r3.z, wl[14], acc); acc = fmaf(r3.w, wl[15], acc);
                acc = fmaf(r4.x, wl[16], acc); acc = fmaf(r4.y, wl[17], acc);
                acc = fmaf(r4.z, wl[18], acc); acc = fmaf(r4.w, wl[19], acc);
                (sq ? outB : outA)[t] = acc;
            }
        };

        produce(0, 0);
        produce(1, 0);
        for (int kt = 0; kt < NT; ++kt) {
            __syncthreads();                       // release tiles kt
            if (kt + 1 < NT) {
                produce(0, kt + 1);
                produce(1, kt + 1);
            }
            if (kt >= 1) {
                flush(0, kt - 1);
                flush(1, kt - 1);
            }
        }
        __syncthreads();                           // consumer's last tiles visible
        flush(0, NT - 1);
        flush(1, NT - 1);
    }
}

extern "C" void kernel_launch(void* const* d_in, const int* in_sizes, int n_in,
                              void* d_out, int out_size, void* d_ws, size_t ws_size,
                              hipStream_t stream) {
    const float* x       = (const float*)d_in[0];
    const float* wih_mu  = (const float*)d_in[1];
    const float* wih_rho = (const float*)d_in[2];
    const float* wih_eps = (const float*)d_in[3];
    const float* whh_mu  = (const float*)d_in[4];
    const float* whh_rho = (const float*)d_in[5];
    const float* whh_eps = (const float*)d_in[6];
    const float* bmu     = (const float*)d_in[7];
    const float* brho    = (const float*)d_in[8];
    const float* beps    = (const float*)d_in[9];
    const float* wlin    = (const float*)d_in[10];
    const float* blin    = (const float*)d_in[11];
    float* out = (float*)d_out;

    const int B = in_sizes[0] / (TSEQ * DIN);   // 256
    const int pairs = (B + 1) / 2;              // odd B: last pair duplicates

    blstm_pair<<<pairs, 128, 0, stream>>>(x, wih_mu, wih_rho, wih_eps,
                                          whh_mu, whh_rho, whh_eps,
                                          bmu, brho, beps, wlin, blin, out, B);
}